// Round 1
// baseline (1901.668 us; speedup 1.0000x reference)
//
#include <hip/hip_runtime.h>
#include <cstdint>

typedef __attribute__((ext_vector_type(8))) __bf16 bf16x8;
typedef __attribute__((ext_vector_type(4))) float f32x4;
typedef __attribute__((ext_vector_type(4))) unsigned int uint4v;
typedef __attribute__((ext_vector_type(4))) float float4v;

__device__ __forceinline__ unsigned short f2bf(float x){
  union { float f; unsigned u; } v; v.f = x;
  unsigned r = v.u + 0x7FFFu + ((v.u >> 16) & 1u);
  return (unsigned short)(r >> 16);
}
__device__ __forceinline__ float bf2f(unsigned short h){
  union { unsigned u; float f; } v; v.u = ((unsigned)h) << 16;
  return v.f;
}
__device__ __forceinline__ float bflo(unsigned u){
  union { unsigned x; float f; } v; v.x = u << 16; return v.f;
}
__device__ __forceinline__ float bfhi(unsigned u){
  union { unsigned x; float f; } v; v.x = u & 0xFFFF0000u; return v.f;
}
__device__ __forceinline__ f32x4 MFMA16(bf16x8 a, bf16x8 b, f32x4 c){
  return __builtin_amdgcn_mfma_f32_16x16x32_bf16(a, b, c, 0, 0, 0);
}

// ---------------- prep: bf16 conversions + transposes ----------------
__global__ __launch_bounds__(256) void prep_k(
    const float* __restrict__ wih, const float* __restrict__ whh,
    const float* __restrict__ wl, const float* __restrict__ wr,
    const float* __restrict__ bl, const float* __restrict__ br,
    const float* __restrict__ fcw,
    unsigned short* __restrict__ wihb, unsigned short* __restrict__ whhb,
    unsigned short* __restrict__ wlrT, unsigned short* __restrict__ fcwT,
    float* __restrict__ blbr){
  int i = blockIdx.x*256 + threadIdx.x;
  if (i < 196608){ wihb[i] = f2bf(wih[i]); return; }
  i -= 196608;
  if (i < 196608){ whhb[i] = f2bf(whh[i]); return; }
  i -= 196608;
  if (i < 655360){
    int n = i >> 8, k = i & 255;
    float v = (n < 1280) ? wl[k*1280 + n] : wr[k*1280 + (n-1280)];
    wlrT[i] = f2bf(v); return;
  }
  i -= 655360;
  if (i < 802816){
    int n = i / 3136, k = i - n*3136;
    fcwT[i] = f2bf(fcw[k*256 + n]); return;
  }
  i -= 802816;
  if (i < 2560){
    blbr[i] = (i < 1280) ? bl[i] : br[i-1280];
  }
}

// ---------------- conv1: [256,3,84,84] -> bf16 [256,32,20,20], s=4 k=8, relu ----
__global__ __launch_bounds__(256) void conv1_k(const float* __restrict__ in,
              const float* __restrict__ w, const float* __restrict__ bias,
              unsigned short* __restrict__ out){
  __shared__ float in_s[3][24][84];
  __shared__ float w_s[32][3][8][8];
  __shared__ float b_s[32];
  int bid = blockIdx.x; int b = bid >> 2, q = bid & 3;
  int t = threadIdx.x;
  for (int idx = t; idx < 3*24*84; idx += 256){
    int ic = idx / (24*84); int rem = idx - ic*(24*84);
    int iy = rem / 84, ix = rem - iy*84;
    in_s[ic][iy][ix] = in[((size_t)(b*3+ic)*84 + (q*20 + iy))*84 + ix];
  }
  for (int idx = t; idx < 32*192; idx += 256) ((float*)w_s)[idx] = w[idx];
  if (t < 32) b_s[t] = bias[t];
  __syncthreads();
  for (int p = t; p < 800; p += 256){
    int oc = p / 25; int rem = p - oc*25;
    int oy = rem / 5, og = rem - oy*5;
    float a0=b_s[oc],a1=b_s[oc],a2=b_s[oc],a3=b_s[oc];
    #pragma unroll
    for (int ic=0;ic<3;ic++){
      #pragma unroll
      for (int ky=0;ky<8;ky++){
        const float* row = &in_s[ic][oy*4+ky][og*16];
        float s[20];
        #pragma unroll
        for (int cc=0;cc<20;cc++) s[cc]=row[cc];
        const float* wp = &w_s[oc][ic][ky][0];
        #pragma unroll
        for (int kx=0;kx<8;kx++){
          float wv = wp[kx];
          a0 += s[kx]*wv; a1 += s[4+kx]*wv; a2 += s[8+kx]*wv; a3 += s[12+kx]*wv;
        }
      }
    }
    size_t ob = ((size_t)(b*32+oc)*20 + (q*5+oy))*20 + og*4;
    out[ob+0]=f2bf(fmaxf(a0,0.f)); out[ob+1]=f2bf(fmaxf(a1,0.f));
    out[ob+2]=f2bf(fmaxf(a2,0.f)); out[ob+3]=f2bf(fmaxf(a3,0.f));
  }
}

// ---------------- conv2: bf16 [256,32,20,20] -> bf16 [256,64,9,9], s=2 k=4 ----
__global__ __launch_bounds__(256) void conv2_k(const unsigned short* __restrict__ in,
              const float* __restrict__ w, const float* __restrict__ bias,
              unsigned short* __restrict__ out){
  __shared__ unsigned short in_s[32][20][20];
  __shared__ float w_s[16][32][4][4];
  __shared__ float b_s[16];
  int bid = blockIdx.x; int b = bid >> 2, h = bid & 3;
  int t = threadIdx.x;
  for (int idx = t; idx < 32*400; idx += 256) ((unsigned short*)in_s)[idx] = in[(size_t)b*12800 + idx];
  for (int idx = t; idx < 16*512; idx += 256) ((float*)w_s)[idx] = w[h*8192 + idx];
  if (t < 16) b_s[t] = bias[h*16 + t];
  __syncthreads();
  for (int p = t; p < 432; p += 256){
    int ocl = p / 27; int rem = p - ocl*27;
    int oy = rem / 3, og = rem - oy*3;
    float a0=b_s[ocl],a1=b_s[ocl],a2=b_s[ocl];
    #pragma unroll 4
    for (int ic=0;ic<32;ic++){
      #pragma unroll
      for (int ky=0;ky<4;ky++){
        const unsigned short* row = &in_s[ic][oy*2+ky][og*6];
        float s[8];
        #pragma unroll
        for (int cc=0;cc<8;cc++) s[cc]=bf2f(row[cc]);
        const float* wp = &w_s[ocl][ic][ky][0];
        #pragma unroll
        for (int kx=0;kx<4;kx++){
          float wv = wp[kx];
          a0 += s[kx]*wv; a1 += s[2+kx]*wv; a2 += s[4+kx]*wv;
        }
      }
    }
    size_t ob = ((size_t)(b*64 + h*16+ocl)*9 + oy)*9 + og*3;
    out[ob+0]=f2bf(fmaxf(a0,0.f)); out[ob+1]=f2bf(fmaxf(a1,0.f)); out[ob+2]=f2bf(fmaxf(a2,0.f));
  }
}

// ---------------- conv3: bf16 [256,64,9,9] -> bf16 [256,3136] (flat NCHW), s=1 k=3 ----
__global__ __launch_bounds__(256) void conv3_k(const unsigned short* __restrict__ in,
              const float* __restrict__ w, const float* __restrict__ bias,
              unsigned short* __restrict__ out){
  __shared__ unsigned short in_s[64][9][9];
  __shared__ float w_s[16][64][3][3];
  __shared__ float b_s[16];
  int bid = blockIdx.x; int b = bid >> 2, h = bid & 3;
  int t = threadIdx.x;
  for (int idx = t; idx < 64*81; idx += 256) ((unsigned short*)in_s)[idx] = in[(size_t)b*5184 + idx];
  for (int idx = t; idx < 16*576; idx += 256) ((float*)w_s)[idx] = w[h*9216 + idx];
  if (t < 16) b_s[t] = bias[h*16 + t];
  __syncthreads();
  for (int p = t; p < 224; p += 256){
    int ocl = p / 14; int rem = p - ocl*14;
    int oy = rem >> 1, og = rem & 1;
    int ox0 = og*4; int nx = og ? 3 : 4;
    float a[4]; a[0]=a[1]=a[2]=a[3]=b_s[ocl];
    for (int ic=0;ic<64;ic++){
      #pragma unroll
      for (int ky=0;ky<3;ky++){
        const unsigned short* row = &in_s[ic][oy+ky][ox0];
        float s[6];
        #pragma unroll
        for (int cc=0;cc<6;cc++) s[cc] = (ox0+cc < 9) ? bf2f(row[cc]) : 0.f;
        const float* wp = &w_s[ocl][ic][ky][0];
        #pragma unroll
        for (int kx=0;kx<3;kx++){
          float wv = wp[kx];
          #pragma unroll
          for (int jj=0;jj<4;jj++) a[jj] += s[jj+kx]*wv;
        }
      }
    }
    size_t ob = (size_t)b*3136 + (h*16+ocl)*49 + oy*7 + ox0;
    #pragma unroll
    for (int jj=0;jj<4;jj++) if (jj < nx) out[ob+jj] = f2bf(fmaxf(a[jj],0.f));
  }
}

// ---------------- generic MFMA GEMM: C[m,n] = act(A[m,:]·B[n,:] + bias[n]) ----
// A [M][K] bf16 rowmajor, B [N][K] bf16 rowmajor, C written bf16 at (m*rowmul)*ldc + n
__global__ __launch_bounds__(256) void gemm_k(const unsigned short* __restrict__ A,
              const unsigned short* __restrict__ B, const float* __restrict__ bias,
              unsigned short* __restrict__ C, int K, int ldc, int rowmul, int relu, int Nblk){
  __shared__ __align__(16) unsigned short As[64*32];
  __shared__ __align__(16) unsigned short Bs[64*32];
  int bid = blockIdx.x;
  int nb = bid % Nblk, mb = bid / Nblk;
  int t = threadIdx.x;
  int w = t >> 6, l = t & 63, lr = l & 15, lh = l >> 4;
  int sr = t >> 2, sq = t & 3;
  f32x4 acc[4];
  #pragma unroll
  for (int i=0;i<4;i++) acc[i] = (f32x4){0.f,0.f,0.f,0.f};
  int nkk = K >> 5;
  const size_t a_row = (size_t)(mb*64 + sr)*K;
  const size_t b_row = (size_t)(nb*64 + sr)*K;
  for (int kk=0;kk<nkk;kk++){
    uint4v av = *(const uint4v*)&A[a_row + kk*32 + sq*8];
    uint4v bv = *(const uint4v*)&B[b_row + kk*32 + sq*8];
    __syncthreads();
    *(uint4v*)((char*)As + ((sr*64 + sq*16) ^ ((sr&3)<<4))) = av;
    *(uint4v*)((char*)Bs + ((sr*64 + sq*16) ^ ((sr&3)<<4))) = bv;
    __syncthreads();
    int brow = w*16 + lr;
    bf16x8 bfr = *(const bf16x8*)((char*)Bs + ((brow*64 + lh*16) ^ ((brow&3)<<4)));
    #pragma unroll
    for (int mt=0;mt<4;mt++){
      int arow = mt*16 + lr;
      bf16x8 afr = *(const bf16x8*)((char*)As + ((arow*64 + lh*16) ^ ((arow&3)<<4)));
      acc[mt] = MFMA16(afr, bfr, acc[mt]);
    }
  }
  int col = nb*64 + w*16 + lr;
  float bn = bias[col];
  #pragma unroll
  for (int mt=0;mt<4;mt++){
    #pragma unroll
    for (int r=0;r<4;r++){
      int row = mb*64 + mt*16 + lh*4 + r;
      float v = acc[mt][r] + bn;
      if (relu) v = fmaxf(v, 0.f);
      C[(size_t)row*rowmul*ldc + col] = f2bf(v);
    }
  }
}

// ---------------- fused MLP+GRU persistent kernel ----------------
// 192 blocks x 256 threads; each block owns 32 sequence rows; 50 timesteps.
__global__ __launch_bounds__(256) void gru_k(const float* __restrict__ obs,
              const float* __restrict__ mlpw, const float* __restrict__ mlpb,
              const unsigned short* __restrict__ wihb, const unsigned short* __restrict__ whhb,
              const float* __restrict__ bih, const float* __restrict__ bhh,
              unsigned short* __restrict__ nemb){
  __shared__ __align__(16) float obs_s[32][16];
  __shared__ __align__(16) unsigned short mlp_s[16*256];
  __shared__ __align__(16) float mlpb_s[256];
  __shared__ __align__(16) unsigned short emb_s[32*256];  // swizzled
  __shared__ __align__(16) unsigned short hb_s[32*256];   // swizzled

  const int t = threadIdx.x, blk = blockIdx.x;
  for (int j = t; j < 4096; j += 256) mlp_s[j] = f2bf(mlpw[j]);
  mlpb_s[t] = mlpb[t];
  for (int j = t; j < 8192; j += 256) hb_s[j] = 0;

  const int w = t >> 6, l = t & 63, lr = l & 15, lh = l >> 4;
  float bR[4], bZ[4], bXN[4], bHN[4];
  #pragma unroll
  for (int it=0; it<4; it++){
    int i = w*64 + it*16 + lr;
    bR[it]  = bih[i]      + bhh[i];
    bZ[it]  = bih[256+i]  + bhh[256+i];
    bXN[it] = bih[512+i];
    bHN[it] = bhh[512+i];
  }
  const int em = t >> 3, en0 = (t & 7) << 5;

  int lrow = t >> 2, lc4 = (t & 3) << 2;
  int rrL = blk*32 + lrow; int bL = rrL/24, ndL = 1 + (rrL - bL*24);
  const float* obase = obs + (size_t)(bL*25 + ndL)*800 + lc4;

  __syncthreads();

  for (int step=0; step<50; step++){
    if (t < 128){
      *(float4v*)&obs_s[lrow][lc4] = *(const float4v*)(obase + (size_t)step*16);
    }
    __syncthreads();
    // ---- MLP emb (fp32 VALU) ----
    {
      float o[16];
      #pragma unroll
      for (int k=0;k<16;k++) o[k] = obs_s[em][k];
      float acc[32];
      #pragma unroll
      for (int j=0;j<32;j++) acc[j] = mlpb_s[en0+j];
      #pragma unroll
      for (int k=0;k<16;k++){
        #pragma unroll
        for (int j8=0;j8<4;j8++){
          uint4v wv = *(const uint4v*)&mlp_s[k*256 + en0 + j8*8];
          #pragma unroll
          for (int q=0;q<4;q++){
            acc[j8*8+2*q]   += o[k]*bflo(wv[q]);
            acc[j8*8+2*q+1] += o[k]*bfhi(wv[q]);
          }
        }
      }
      #pragma unroll
      for (int j8=0;j8<4;j8++){
        uint4v pk;
        #pragma unroll
        for (int q=0;q<4;q++){
          float x0 = fmaxf(acc[j8*8+2*q],0.f), x1 = fmaxf(acc[j8*8+2*q+1],0.f);
          pk[q] = (unsigned)f2bf(x0) | ((unsigned)f2bf(x1) << 16);
        }
        int byte = (em*512 + (en0 + j8*8)*2) ^ ((em&7)<<4);
        *(uint4v*)((char*)emb_s + byte) = pk;
      }
    }
    __syncthreads();
    // ---- MFMA: rz (fused K), xn, hn ----
    f32x4 aR[2][4], aZ[2][4], aXN[2][4], aHN[2][4];
    #pragma unroll
    for (int mt=0;mt<2;mt++)
      #pragma unroll
      for (int it=0;it<4;it++){
        aR[mt][it]=(f32x4){0,0,0,0}; aZ[mt][it]=(f32x4){0,0,0,0};
        aXN[mt][it]=(f32x4){0,0,0,0}; aHN[mt][it]=(f32x4){0,0,0,0};
      }
    #pragma unroll 1
    for (int kk=0;kk<8;kk++){
      bf16x8 aE[2], aH[2];
      #pragma unroll
      for (int mt=0;mt<2;mt++){
        int row = mt*16 + lr;
        int byte = (row*512 + (kk*32 + lh*8)*2) ^ ((row&7)<<4);
        aE[mt] = *(const bf16x8*)((char*)emb_s + byte);
        aH[mt] = *(const bf16x8*)((char*)hb_s + byte);
      }
      int ko = kk*32 + lh*8;
      #pragma unroll
      for (int it=0;it<4;it++){
        int n = w*64 + it*16 + lr;
        bf16x8 bWr = *(const bf16x8*)&wihb[(size_t)n*256 + ko];
        bf16x8 bHr = *(const bf16x8*)&whhb[(size_t)n*256 + ko];
        bf16x8 bWz = *(const bf16x8*)&wihb[(size_t)(256+n)*256 + ko];
        bf16x8 bHz = *(const bf16x8*)&whhb[(size_t)(256+n)*256 + ko];
        bf16x8 bWn = *(const bf16x8*)&wihb[(size_t)(512+n)*256 + ko];
        bf16x8 bHn = *(const bf16x8*)&whhb[(size_t)(512+n)*256 + ko];
        #pragma unroll
        for (int mt=0;mt<2;mt++){
          aR[mt][it]  = MFMA16(aE[mt], bWr, aR[mt][it]);
          aR[mt][it]  = MFMA16(aH[mt], bHr, aR[mt][it]);
          aZ[mt][it]  = MFMA16(aE[mt], bWz, aZ[mt][it]);
          aZ[mt][it]  = MFMA16(aH[mt], bHz, aZ[mt][it]);
          aXN[mt][it] = MFMA16(aE[mt], bWn, aXN[mt][it]);
          aHN[mt][it] = MFMA16(aH[mt], bHn, aHN[mt][it]);
        }
      }
    }
    __syncthreads();
    // ---- gate update ----
    #pragma unroll
    for (int mt=0;mt<2;mt++){
      #pragma unroll
      for (int it=0;it<4;it++){
        #pragma unroll
        for (int r=0;r<4;r++){
          int m = mt*16 + lh*4 + r;
          int i = w*64 + it*16 + lr;
          float rp = aR[mt][it][r] + bR[it];
          float zp = aZ[mt][it][r] + bZ[it];
          float xn = aXN[mt][it][r] + bXN[it];
          float hn = aHN[mt][it][r] + bHN[it];
          float rg = 1.f/(1.f + __expf(-rp));
          float zg = 1.f/(1.f + __expf(-zp));
          float nv = tanhf(xn + rg*hn);
          int byte = (m*512 + i*2) ^ ((m&7)<<4);
          unsigned short* hp = (unsigned short*)((char*)hb_s + byte);
          float hold = bf2f(*hp);
          *hp = f2bf((1.f-zg)*nv + zg*hold);
        }
      }
    }
    __syncthreads();
  }
  for (int j=0;j<32;j++){
    int rr = blk*32 + j; int b = rr/24, nd = 1 + (rr - b*24);
    int byte = (j*512 + t*2) ^ ((j&7)<<4);
    nemb[(size_t)(b*25+nd)*256 + t] = *(const unsigned short*)((char*)hb_s + byte);
  }
}

// ---------------- GAT scores + softmax + node0 out + dueling head ----------------
__global__ __launch_bounds__(256) void gat_k(const int* __restrict__ edges,
              const unsigned short* __restrict__ glgr,
              const float* __restrict__ att, const float* __restrict__ gbias,
              const float* __restrict__ hidw, const float* __restrict__ hidb,
              const float* __restrict__ outw, const float* __restrict__ outb,
              const float* __restrict__ advw, const float* __restrict__ advb,
              float* __restrict__ out){
  __shared__ int src_s[125], dst_s[125];
  __shared__ __align__(16) float att_s[1280];
  __shared__ float sc[125][5], al[125][5];
  __shared__ float mx[25][5], dn[25][5];
  __shared__ float g0[256], hh[256];
  __shared__ float adv_s[8], v_s;
  __shared__ int e0[125]; __shared__ int ne0;

  int b = blockIdx.x, t = threadIdx.x;
  if (t < 100){ src_s[t] = edges[b*200 + t]; dst_s[t] = edges[b*200 + 100 + t]; }
  else if (t < 125){ src_s[t] = t - 100; dst_s[t] = t - 100; }
  for (int j = t; j < 1280; j += 256) att_s[j] = att[j];
  __syncthreads();
  if (t == 0){ int c = 0; for (int e=0;e<125;e++) if (dst_s[e]==0) e0[c++]=e; ne0 = c; }
  const unsigned short* gbase = glgr + (size_t)b*25*2560;
  for (int p = t; p < 625; p += 256){
    int e = p/5, h = p - 5*(p/5);
    const unsigned short* glp = gbase + src_s[e]*2560 + h*256;
    const unsigned short* grp = gbase + dst_s[e]*2560 + 1280 + h*256;
    const float* ap = &att_s[h*256];
    float acc = 0.f;
    #pragma unroll 4
    for (int c=0;c<256;c+=8){
      uint4v gu = *(const uint4v*)&glp[c];
      uint4v ru = *(const uint4v*)&grp[c];
      #pragma unroll
      for (int q=0;q<4;q++){
        float s0 = bflo(gu[q]) + bflo(ru[q]);
        float s1 = bfhi(gu[q]) + bfhi(ru[q]);
        s0 = (s0 > 0.f) ? s0 : 0.2f*s0;
        s1 = (s1 > 0.f) ? s1 : 0.2f*s1;
        acc += s0*ap[c+2*q] + s1*ap[c+2*q+1];
      }
    }
    sc[e][h] = acc;
  }
  __syncthreads();
  if (t < 125){
    int j = t/5, h = t - 5*(t/5);
    float m = -1e30f;
    for (int e=0;e<125;e++) if (dst_s[e]==j) m = fmaxf(m, sc[e][h]);
    float d = 0.f;
    for (int e=0;e<125;e++) if (dst_s[e]==j) d += __expf(sc[e][h]-m);
    mx[j][h] = m; dn[j][h] = d;
  }
  __syncthreads();
  for (int p = t; p < 625; p += 256){
    int e = p/5, h = p - 5*(p/5);
    int dd = dst_s[e];
    al[e][h] = __expf(sc[e][h] - mx[dd][h]) / dn[dd][h];
  }
  __syncthreads();
  if (t < 101){
    out[2048 + b*101 + t] = (al[t][0]+al[t][1]+al[t][2]+al[t][3]+al[t][4])*0.2f;
  }
  {
    float acc = 0.f;
    for (int x=0;x<ne0;x++){
      int e = e0[x]; int s = src_s[e];
      const unsigned short* glp = gbase + s*2560 + t;
      #pragma unroll
      for (int h=0;h<5;h++) acc += al[e][h]*bf2f(glp[h*256]);
    }
    g0[t] = acc*0.2f + gbias[t];
  }
  __syncthreads();
  {
    float acc = hidb[t];
    for (int k=0;k<256;k++) acc += g0[k]*hidw[k*256+t];
    hh[t] = fmaxf(acc, 0.f);
  }
  __syncthreads();
  if (t < 8){
    float acc = advb[t];
    for (int k=0;k<256;k++) acc += hh[k]*advw[k*8+t];
    adv_s[t] = acc;
  } else if (t == 8){
    float acc = outb[0];
    for (int k=0;k<256;k++) acc += hh[k]*outw[k];
    v_s = acc;
  }
  __syncthreads();
  if (t < 8){
    float m = adv_s[0]+adv_s[1]+adv_s[2]+adv_s[3]+adv_s[4]+adv_s[5]+adv_s[6]+adv_s[7];
    out[b*8+t] = v_s + adv_s[t] - m*0.125f;
  }
}

extern "C" void kernel_launch(void* const* d_in, const int* in_sizes, int n_in,
                              void* d_out, int out_size, void* d_ws, size_t ws_size,
                              hipStream_t stream){
  const float* obs     = (const float*)d_in[0];
  const float* obs_map = (const float*)d_in[1];
  const int*   edges   = (const int*)d_in[2];
  const float* mlp_w = (const float*)d_in[4];
  const float* mlp_b = (const float*)d_in[5];
  const float* c1w = (const float*)d_in[6];  const float* c1b = (const float*)d_in[7];
  const float* c2w = (const float*)d_in[8];  const float* c2b = (const float*)d_in[9];
  const float* c3w = (const float*)d_in[10]; const float* c3b = (const float*)d_in[11];
  const float* fcw = (const float*)d_in[12]; const float* fcb = (const float*)d_in[13];
  const float* wih = (const float*)d_in[14]; const float* whh = (const float*)d_in[15];
  const float* bih = (const float*)d_in[16]; const float* bhh = (const float*)d_in[17];
  const float* gwl = (const float*)d_in[18]; const float* gbl = (const float*)d_in[19];
  const float* gwr = (const float*)d_in[20]; const float* gbr = (const float*)d_in[21];
  const float* gatt = (const float*)d_in[22]; const float* gbias = (const float*)d_in[23];
  const float* hidw = (const float*)d_in[24]; const float* hidb = (const float*)d_in[25];
  const float* outw = (const float*)d_in[26]; const float* outb = (const float*)d_in[27];
  const float* advw = (const float*)d_in[28]; const float* advb = (const float*)d_in[29];
  float* out = (float*)d_out;
  char* ws = (char*)d_ws;

  // workspace layout (conv buffers aliased under glgr; consumed before glgr write)
  unsigned short* c1o  = (unsigned short*)(ws + 0);          // 6,553,600 B
  unsigned short* c2o  = (unsigned short*)(ws + 6553600);    // 2,654,208 B
  unsigned short* c3o  = (unsigned short*)(ws + 9207808);    // 1,605,632 B
  unsigned short* glgr = (unsigned short*)(ws + 0);          // 32,768,000 B
  size_t o = 32768000;
  unsigned short* nemb = (unsigned short*)(ws + o); o += 3276800;
  unsigned short* wihb = (unsigned short*)(ws + o); o += 393216;
  unsigned short* whhb = (unsigned short*)(ws + o); o += 393216;
  unsigned short* wlrT = (unsigned short*)(ws + o); o += 1310720;
  unsigned short* fcwT = (unsigned short*)(ws + o); o += 1605632;
  float* blbr          = (float*)(ws + o); o += 10240;

  prep_k<<<7242, 256, 0, stream>>>(wih, whh, gwl, gwr, gbl, gbr, fcw, wihb, whhb, wlrT, fcwT, blbr);
  conv1_k<<<1024, 256, 0, stream>>>(obs_map, c1w, c1b, c1o);
  conv2_k<<<1024, 256, 0, stream>>>(c1o, c2w, c2b, c2o);
  conv3_k<<<1024, 256, 0, stream>>>(c2o, c3w, c3b, c3o);
  gemm_k<<<16, 256, 0, stream>>>(c3o, fcwT, fcb, nemb, 3136, 256, 25, 1, 4);      // FC -> node 0
  gru_k<<<192, 256, 0, stream>>>(obs, mlp_w, mlp_b, wihb, whhb, bih, bhh, nemb);  // nodes 1..24
  gemm_k<<<4000, 256, 0, stream>>>(nemb, wlrT, blbr, glgr, 256, 2560, 1, 0, 40);  // gl|gr
  gat_k<<<256, 256, 0, stream>>>(edges, glgr, gatt, gbias, hidw, hidb, outw, outb, advw, advb, out);
}